// Round 5
// baseline (12564.571 us; speedup 1.0000x reference)
//
#include <hip/hip_runtime.h>
#include <hip/hip_bf16.h>

// Bidirectional LSTM w/ field gates. B=128,T=256,I=H=1024,F=64. FP32 I/O.
// Round 5 (resubmit of R4; lost to GPU acquisition timeout):
// precompute x@W_ih^T+b and fp@W_fp^T+b_fp in 32-step chunks (bf16 in ws);
// recurrent step kernel only h@W_hh^T (K=1024) at 8 waves/block, grid 256.

#define Bn 128
#define Tn 256
#define In 1024
#define Hn 1024
#define Fn 64
#define CH 32   // chunk length (steps)

typedef __attribute__((ext_vector_type(8))) short short8;
typedef __attribute__((ext_vector_type(4))) short short4v;
typedef __attribute__((ext_vector_type(4))) float f32x4;

__device__ __forceinline__ float bf2f(short u) {
  union { unsigned int i; float f; } x;
  x.i = ((unsigned int)(unsigned short)u) << 16;
  return x.f;
}
__device__ __forceinline__ unsigned short f2bf(float f) {
  __hip_bfloat16 h = __float2bfloat16(f);
  return *reinterpret_cast<unsigned short*>(&h);
}
__device__ __forceinline__ float sigm(float x) { return 1.0f / (1.0f + __expf(-x)); }
__device__ __forceinline__ float tanh_(float x) { return 1.0f - 2.0f / (1.0f + __expf(2.0f * x)); }

__global__ void f32_to_bf16_vec(const float* __restrict__ src, short* __restrict__ dst, int n4) {
  for (int i = blockIdx.x * blockDim.x + threadIdx.x; i < n4; i += gridDim.x * blockDim.x) {
    const float4 v = ((const float4*)src)[i];
    short4v o;
    o[0] = (short)f2bf(v.x); o[1] = (short)f2bf(v.y);
    o[2] = (short)f2bf(v.z); o[3] = (short)f2bf(v.w);
    ((short4v*)dst)[i] = o;
  }
}

__global__ void init_state(float* __restrict__ c_state, unsigned int* __restrict__ h0w) {
  const int i = blockIdx.x * blockDim.x + threadIdx.x;
  if (i < 2 * Bn * Hn) c_state[i] = 0.0f;
  if (i < (2 * Bn * Hn) / 2) h0w[i] = 0u;
}

// gates_x precompute for one chunk: gx[dir][sl][bat][4096] = x_t @ W_ih^T + b.
// grid (64 ntiles, 64 rowtiles, 2 dirs), 512 thr (8 waves). Tile M=64,N=64.
// wave w: m-frag mf=w&3, n-frag pair nfp=w>>2.
__global__ __launch_bounds__(512) void precompute_gx(
    const short* __restrict__ seq_bf,
    const short* __restrict__ Wih_f, const short* __restrict__ Wih_b,
    const float* __restrict__ b_f, const float* __restrict__ b_b,
    short* __restrict__ gx, int c0)
{
  const int n0 = blockIdx.x * 64;
  const int row0 = blockIdx.y * 64;
  const int dir = blockIdx.z;
  const int tid = threadIdx.x, lane = tid & 63, w = tid >> 6;
  const int l15 = lane & 15, lk = lane >> 4;
  const int mf = w & 3, nfp = w >> 2;

  const short* Wih = dir ? Wih_b : Wih_f;
  const float* bg  = dir ? b_b   : b_f;

  const int grow = row0 + mf * 16 + l15;          // A row
  const int sl = grow >> 7, bat = grow & 127;
  const int t = dir ? (Tn - 1 - (c0 + sl)) : (c0 + sl);
  const short* xrow = seq_bf + ((size_t)bat * Tn + t) * In + lk * 8;

  const short* br[2];
#pragma unroll
  for (int q = 0; q < 2; ++q)
    br[q] = Wih + (size_t)(n0 + (nfp * 2 + q) * 16 + l15) * In + lk * 8;

  f32x4 acc[2];
  acc[0] = (f32x4){0.f,0.f,0.f,0.f}; acc[1] = (f32x4){0.f,0.f,0.f,0.f};
  for (int k = 0; k < In; k += 32) {
    const short8 a = *(const short8*)(xrow + k);
#pragma unroll
    for (int q = 0; q < 2; ++q) {
      const short8 b = *(const short8*)(br[q] + k);
      acc[q] = __builtin_amdgcn_mfma_f32_16x16x32_bf16(a, b, acc[q], 0, 0, 0);
    }
  }
#pragma unroll
  for (int q = 0; q < 2; ++q) {
    const int col = n0 + (nfp * 2 + q) * 16 + l15;
    const float bias = bg[col];
#pragma unroll
    for (int r = 0; r < 4; ++r) {
      const int grow2 = row0 + mf * 16 + lk * 4 + r;    // D row
      const int sl2 = grow2 >> 7, bat2 = grow2 & 127;
      gx[(((size_t)dir * CH + sl2) * Bn + bat2) * (4 * Hn) + col] =
          (short)f2bf(acc[q][r] + bias);
    }
  }
}

// field-gate precompute: fg[dir][sl][bat][2048] = fp_t @ W_fp^T + b_fp. K=64.
// grid (32 ntiles, 64 rowtiles, 2 dirs), 512 thr.
__global__ __launch_bounds__(512) void precompute_fg(
    const short* __restrict__ fpos_bf,
    const short* __restrict__ Wfp_f, const short* __restrict__ Wfp_b,
    const float* __restrict__ bfp_f, const float* __restrict__ bfp_b,
    short* __restrict__ fg, int c0)
{
  const int n0 = blockIdx.x * 64;
  const int row0 = blockIdx.y * 64;
  const int dir = blockIdx.z;
  const int tid = threadIdx.x, lane = tid & 63, w = tid >> 6;
  const int l15 = lane & 15, lk = lane >> 4;
  const int mf = w & 3, nfp = w >> 2;

  const short* Wfp = dir ? Wfp_b : Wfp_f;
  const float* bfp = dir ? bfp_b : bfp_f;

  const int grow = row0 + mf * 16 + l15;
  const int sl = grow >> 7, bat = grow & 127;
  const int t = dir ? (Tn - 1 - (c0 + sl)) : (c0 + sl);
  const short* frow = fpos_bf + ((size_t)bat * Tn + t) * Fn + lk * 8;

  f32x4 acc[2];
  acc[0] = (f32x4){0.f,0.f,0.f,0.f}; acc[1] = (f32x4){0.f,0.f,0.f,0.f};
#pragma unroll
  for (int k = 0; k < Fn; k += 32) {
    const short8 a = *(const short8*)(frow + k);
#pragma unroll
    for (int q = 0; q < 2; ++q) {
      const short8 b = *(const short8*)(Wfp + (size_t)(n0 + (nfp * 2 + q) * 16 + l15) * Fn + lk * 8 + k);
      acc[q] = __builtin_amdgcn_mfma_f32_16x16x32_bf16(a, b, acc[q], 0, 0, 0);
    }
  }
#pragma unroll
  for (int q = 0; q < 2; ++q) {
    const int col = n0 + (nfp * 2 + q) * 16 + l15;
    const float bias = bfp[col];
#pragma unroll
    for (int r = 0; r < 4; ++r) {
      const int grow2 = row0 + mf * 16 + lk * 4 + r;
      const int sl2 = grow2 >> 7, bat2 = grow2 & 127;
      fg[(((size_t)dir * CH + sl2) * Bn + bat2) * (2 * Hn) + col] =
          (short)f2bf(acc[q][r] + bias);
    }
  }
}

// recurrent step: gates = h@W_hh^T (K=1024) + gx; pointwise update.
// grid (64 utiles, 2 dirs, 2 mtiles), 512 thr (8 waves). Tile M=64, N=64
// (4 gates x 16 units). wave w: mf=w&3, gate pair nfp=w>>2.
__global__ __launch_bounds__(512) void lstm_step2(
    const short* __restrict__ Whh_f, const short* __restrict__ Whh_b,
    const short* __restrict__ gx, const short* __restrict__ fg,
    float* __restrict__ c_state,
    const short* __restrict__ h_read, short* __restrict__ h_write,
    float* __restrict__ out, int s, int sl)
{
  const int j0 = blockIdx.x * 16;
  const int dir = blockIdx.y;
  const int m0 = blockIdx.z * 64;
  const int t = dir ? (Tn - 1 - s) : s;
  const int tid = threadIdx.x, lane = tid & 63, w = tid >> 6;
  const int l15 = lane & 15, lk = lane >> 4;
  const int mf = w & 3, nfp = w >> 2;

  const short* Whh = dir ? Whh_b : Whh_f;

  const int abat = m0 + mf * 16 + l15;
  const short* hrow = h_read + ((size_t)dir * Bn + abat) * Hn + lk * 8;
  const short* br[2];
#pragma unroll
  for (int q = 0; q < 2; ++q)
    br[q] = Whh + (size_t)((nfp * 2 + q) * Hn + j0 + l15) * Hn + lk * 8;

  f32x4 acc[2];
  acc[0] = (f32x4){0.f,0.f,0.f,0.f}; acc[1] = (f32x4){0.f,0.f,0.f,0.f};
  for (int k = 0; k < Hn; k += 32) {
    const short8 a = *(const short8*)(hrow + k);
#pragma unroll
    for (int q = 0; q < 2; ++q) {
      const short8 b = *(const short8*)(br[q] + k);
      acc[q] = __builtin_amdgcn_mfma_f32_16x16x32_bf16(a, b, acc[q], 0, 0, 0);
    }
  }

  __shared__ float lds[4][64][17];
#pragma unroll
  for (int q = 0; q < 2; ++q)
#pragma unroll
    for (int r = 0; r < 4; ++r)
      lds[nfp * 2 + q][mf * 16 + lk * 4 + r][l15] = acc[q][r];
  __syncthreads();

  const size_t OUTN = (size_t)Tn * Bn * 2 * Hn;
#pragma unroll
  for (int qq = 0; qq < 2; ++qq) {
    const int p = tid + 512 * qq;
    const int ml = p >> 4, jl = p & 15;
    const int bat = m0 + ml, j = j0 + jl;
    const short* gxb = gx + (((size_t)dir * CH + sl) * Bn + bat) * (4 * Hn);
    const short* fgb = fg + (((size_t)dir * CH + sl) * Bn + bat) * (2 * Hn);
    const float i_g = sigm (lds[0][ml][jl] + bf2f(gxb[j]));
    const float f_g = sigm (lds[1][ml][jl] + bf2f(gxb[Hn + j]));
    const float g_g = tanh_(lds[2][ml][jl] + bf2f(gxb[2 * Hn + j]));
    const float o_g = sigm (lds[3][ml][jl] + bf2f(gxb[3 * Hn + j]));
    const float l_g = sigm (bf2f(fgb[j]));
    const float d_g = tanh_(bf2f(fgb[Hn + j]));
    const size_t cidx = ((size_t)dir * Bn + bat) * Hn + j;
    const float c_new = f_g * c_state[cidx] + i_g * g_g + l_g * d_g;
    const float h_new = o_g * tanh_(c_new);
    c_state[cidx] = c_new;
    h_write[cidx] = (short)f2bf(h_new);
    out[((size_t)t * Bn + bat) * (2 * Hn) + (size_t)dir * Hn + j] = h_new;
    if (s == Tn - 1) {
      out[OUTN + cidx] = h_new;
      out[OUTN + (size_t)2 * Bn * Hn + cidx] = c_new;
    }
  }
}

static inline void conv(const void* src, short* dst, size_t n, hipStream_t stream) {
  int n4 = (int)(n / 4);
  int blocks = (n4 + 255) / 256; if (blocks > 8192) blocks = 8192;
  hipLaunchKernelGGL(f32_to_bf16_vec, dim3(blocks), dim3(256), 0, stream,
                     (const float*)src, dst, n4);
}

extern "C" void kernel_launch(void* const* d_in, const int* in_sizes, int n_in,
                              void* d_out, int out_size, void* d_ws, size_t ws_size,
                              hipStream_t stream) {
  (void)in_sizes; (void)n_in; (void)out_size; (void)ws_size;
  const float* b_f   = (const float*)d_in[4];
  const float* bfp_f = (const float*)d_in[6];
  const float* b_b   = (const float*)d_in[9];
  const float* bfp_b = (const float*)d_in[11];

  char* p = (char*)d_ws;
  float* c_state = (float*)p;            p += (size_t)2 * Bn * Hn * 4;
  short* h0      = (short*)p;            p += (size_t)2 * Bn * Hn * 2;
  short* h1      = (short*)p;            p += (size_t)2 * Bn * Hn * 2;
  short* seq_bf  = (short*)p;            p += (size_t)Bn * Tn * In * 2;
  short* fpos_bf = (short*)p;            p += (size_t)Bn * Tn * Fn * 2;
  short* Wih_bf[2], *Whh_bf[2], *Wfp_bf[2];
  for (int d = 0; d < 2; ++d) { Wih_bf[d] = (short*)p; p += (size_t)4 * Hn * In * 2; }
  for (int d = 0; d < 2; ++d) { Whh_bf[d] = (short*)p; p += (size_t)4 * Hn * Hn * 2; }
  for (int d = 0; d < 2; ++d) { Wfp_bf[d] = (short*)p; p += (size_t)2 * Hn * Fn * 2; }
  short* gx = (short*)p;                 p += (size_t)2 * CH * Bn * 4 * Hn * 2;
  short* fgb = (short*)p;                p += (size_t)2 * CH * Bn * 2 * Hn * 2;
  float* out = (float*)d_out;

  conv(d_in[0], seq_bf,    (size_t)Bn * Tn * In, stream);
  conv(d_in[1], fpos_bf,   (size_t)Bn * Tn * Fn, stream);
  conv(d_in[2], Wih_bf[0], (size_t)4 * Hn * In, stream);
  conv(d_in[3], Whh_bf[0], (size_t)4 * Hn * Hn, stream);
  conv(d_in[5], Wfp_bf[0], (size_t)2 * Hn * Fn, stream);
  conv(d_in[7], Wih_bf[1], (size_t)4 * Hn * In, stream);
  conv(d_in[8], Whh_bf[1], (size_t)4 * Hn * Hn, stream);
  conv(d_in[10], Wfp_bf[1], (size_t)2 * Hn * Fn, stream);

  hipLaunchKernelGGL(init_state, dim3((2 * Bn * Hn + 255) / 256), dim3(256), 0, stream,
                     c_state, (unsigned int*)h0);

  for (int c = 0; c < Tn / CH; ++c) {
    hipLaunchKernelGGL(precompute_gx, dim3(64, CH * Bn / 64, 2), dim3(512), 0, stream,
                       seq_bf, Wih_bf[0], Wih_bf[1], b_f, b_b, gx, c * CH);
    hipLaunchKernelGGL(precompute_fg, dim3(32, CH * Bn / 64, 2), dim3(512), 0, stream,
                       fpos_bf, Wfp_bf[0], Wfp_bf[1], bfp_f, bfp_b, fgb, c * CH);
    for (int sl = 0; sl < CH; ++sl) {
      const int s = c * CH + sl;
      const short* hr = (s & 1) ? h1 : h0;
      short* hw       = (s & 1) ? h0 : h1;
      hipLaunchKernelGGL(lstm_step2, dim3(64, 2, 2), dim3(512), 0, stream,
                         Whh_bf[0], Whh_bf[1], gx, fgb,
                         c_state, hr, hw, out, s, sl);
    }
  }
}